// Round 2
// baseline (209.449 us; speedup 1.0000x reference)
//
#include <hip/hip_runtime.h>

#define N_VERTS 53215
#define EXP_DIM 29
#define SHP_DIM 199
#define HEIGHT_F 450.0f
#define ASPECT_XY (224.0f / 450.0f)

typedef float f4 __attribute__((ext_vector_type(4)));

// Full 64-lane wave sum on the VALU pipe via DPP row ops:
//   row_shr:1,2,4,8 -> 16-lane row sums in lanes 15/31/47/63
//   row_bcast:15    -> lane 31 += rowsum(0..15), lane 63 += rowsum(32..47)
//   row_bcast:31    -> lane 63 += sum(0..31)  => lane 63 holds the total.
#define DPP_ADD_STEP(s, ctrl)                                                  \
  s += __int_as_float(__builtin_amdgcn_update_dpp(                             \
      0, __float_as_int(s), (ctrl), 0xf, 0xf, true))

#define WAVE_REDUCE_3(s0, s1, s2, ctrl)                                        \
  do {                                                                         \
    DPP_ADD_STEP(s0, ctrl); DPP_ADD_STEP(s1, ctrl); DPP_ADD_STEP(s2, ctrl);    \
  } while (0)

__device__ __forceinline__ float dot4(f4 a, f4 b) {
    return a.x * b.x + a.y * b.y + a.z * b.z + a.w * b.w;
}

// Wave-per-vertex GEMV + transform. R2 change: the dominant stream (w_shp,
// 127 MB of the 146 MB mandatory traffic) is loaded as WIDE dwordx4 lane
// loads instead of 12 scalar dword loads per vertex:
//   vertex blob = 597 contiguous floats (rows x|y|z of 199). Lane l loads
//   f4 at float offsets 4l, 256+4l, 512+4l' (l'<21) + one broadcast dword
//   for element 596. 3 wide loads + 1 dword vs 12 dwords -> ~4x fewer VMEM
//   transactions on the hot stream.
// Weight vectors are loop-invariant per lane: element j of the blob has
// component j/199 and PCA index j%199, so per (round, component) we
// precompute a masked alpha f4 (W0x,W0y,W1y,W1z,W2z; boundary-straddling
// lanes get weight split across two vectors). Masked dots then accumulate
// into sx/sy/sz correctly with no per-iteration index math.
// NOTE: blob byte base = v*2388 == 4v (mod 16), so the dwordx4 loads are
// 4B-aligned. gfx9+ flat/global HW supports unaligned access (ROCm default);
// worst case a load splits at a 128B line.
__global__ __launch_bounds__(256, 4) void pca_transform_kernel(
    const float* __restrict__ pose,       // 12
    const float* __restrict__ alpha_exp,  // 29
    const float* __restrict__ alpha_shp,  // 199
    const float* __restrict__ u_base,     // 3*N_VERTS
    const float* __restrict__ w_exp,      // 3*N_VERTS x 29
    const float* __restrict__ w_shp,      // 3*N_VERTS x 199
    float* __restrict__ out)              // N_VERTS x 3
{
    const int lane = threadIdx.x & 63;
    const int gwave =
        __builtin_amdgcn_readfirstlane((int)((blockIdx.x * blockDim.x + threadIdx.x) >> 6));
    const int nwaves = (int)((gridDim.x * blockDim.x) >> 6);

    // Pose: uniform + loop-invariant -> SGPRs.
    const float p0 = pose[0], p1 = pose[1], p2  = pose[2],  p3  = pose[3];
    const float p4 = pose[4], p5 = pose[5], p6  = pose[6],  p7  = pose[7];
    const float p8 = pose[8], p9 = pose[9], p10 = pose[10], p11 = pose[11];
    const float s  = p3 + p7 + p11;

    // ---- Loop-invariant per-lane weights ----------------------------------
    // Exp path (29 floats/row): lane-per-k with clamp+zero, as before.
    const int   ke = (lane < EXP_DIM) ? lane : (EXP_DIM - 1);
    const float ae = (lane < EXP_DIM) ? alpha_exp[ke] : 0.0f;

    // Shp path: masked alpha f4s per round/component.
    // Round 0 covers blob floats j=4l+e in [0,256): components x (j<199), y.
    // Round 1 covers j in [256,512): components y (j<398), z.
    // Round 2 covers j in [512,596): component z only; lanes >= 21 idle.
    // Element 596 (z, alpha[198]) handled as a broadcast dword on lane 0.
    f4 W0x, W0y, W1y, W1z, W2z;
    {
        const int b = 4 * lane;
        #pragma unroll
        for (int e = 0; e < 4; ++e) {
            const int j0 = b + e;
            const int j1 = 256 + b + e;
            const int j2 = 512 + b + e;
            const float w0 = alpha_shp[(j0 < SHP_DIM) ? j0 : (j0 - SHP_DIM)];
            W0x[e] = (j0 < SHP_DIM) ? w0 : 0.0f;
            W0y[e] = (j0 < SHP_DIM) ? 0.0f : w0;
            const float w1 = alpha_shp[(j1 < 2 * SHP_DIM) ? (j1 - SHP_DIM)
                                                          : (j1 - 2 * SHP_DIM)];
            W1y[e] = (j1 < 2 * SHP_DIM) ? w1 : 0.0f;
            W1z[e] = (j1 < 2 * SHP_DIM) ? 0.0f : w1;
            W2z[e] = (j2 <= 595) ? alpha_shp[j2 - 2 * SHP_DIM] : 0.0f;
        }
    }
    const float w596 = (lane == 0) ? alpha_shp[SHP_DIM - 1] : 0.0f;
    const int   l2   = (lane < 21) ? lane : 0;  // clamp round-2 address, wt=0

    for (int v = gwave; v < N_VERTS; v += nwaves) {
        const float* __restrict__ p = w_shp + (size_t)v * (3 * SHP_DIM);
        const float* __restrict__ e = w_exp + (size_t)v * (3 * EXP_DIM);

        // ---- Issue all loads back-to-back (hot stream first) ----
        const f4 q0 = *(const f4*)(p + 4 * lane);          // floats [0,256)
        const f4 q1 = *(const f4*)(p + 256 + 4 * lane);    // floats [256,512)
        const f4 q2 = *(const f4*)(p + 512 + 4 * l2);      // floats [512,596)
        const float t596 = p[596];                         // broadcast line
        const float exv = e[ke];
        const float eyv = e[EXP_DIM + ke];
        const float ezv = e[2 * EXP_DIM + ke];
        // u_base: wave-uniform -> scalar loads, hidden under the FMAs.
        const float ux = u_base[3 * v + 0];
        const float uy = u_base[3 * v + 1];
        const float uz = u_base[3 * v + 2];

        // ---- Masked wide dots: split x/y/z at the row boundaries ----
        float sx = dot4(q0, W0x);
        float sy = dot4(q0, W0y) + dot4(q1, W1y);
        float sz = dot4(q1, W1z) + dot4(q2, W2z) + t596 * w596;
        sx += exv * ae;
        sy += eyv * ae;
        sz += ezv * ae;

        // ---- 6-step DPP tree reduce; totals land in lane 63 ----
        WAVE_REDUCE_3(sx, sy, sz, 0x111);  // row_shr:1
        WAVE_REDUCE_3(sx, sy, sz, 0x112);  // row_shr:2
        WAVE_REDUCE_3(sx, sy, sz, 0x114);  // row_shr:4
        WAVE_REDUCE_3(sx, sy, sz, 0x118);  // row_shr:8
        WAVE_REDUCE_3(sx, sy, sz, 0x142);  // row_bcast:15
        WAVE_REDUCE_3(sx, sy, sz, 0x143);  // row_bcast:31

        const float vx = sx + ux, vy = sy + uy, vz = sz + uz;

        const float ox = ASPECT_XY * (s * (p0 * vx + p1 * vy + p2  * vz) + p3);
        const float oy = ASPECT_XY * (HEIGHT_F - (s * (p4 * vx + p5 * vy + p6 * vz) + p7));
        const float oz = s * (p8 * vx + p9 * vy + p10 * vz);

        if (lane == 63) {
            float* o = out + (size_t)v * 3;
            o[0] = ox; o[1] = oy; o[2] = oz;
        }
    }
}

extern "C" void kernel_launch(void* const* d_in, const int* in_sizes, int n_in,
                              void* d_out, int out_size, void* d_ws, size_t ws_size,
                              hipStream_t stream) {
    const float* pose      = (const float*)d_in[0];
    const float* alpha_exp = (const float*)d_in[1];
    const float* alpha_shp = (const float*)d_in[2];
    const float* u_base    = (const float*)d_in[3];
    const float* w_exp     = (const float*)d_in[4];
    const float* w_shp     = (const float*)d_in[5];
    float* out = (float*)d_out;

    // 2048 blocks x 256 thr = 8192 waves, wave-per-vertex grid-stride
    // (~6.5 vertices/wave). 16 waves/CU at __launch_bounds__(256,4).
    pca_transform_kernel<<<2048, 256, 0, stream>>>(
        pose, alpha_exp, alpha_shp, u_base, w_exp, w_shp, out);
}